// Round 9
// baseline (411.137 us; speedup 1.0000x reference)
//
#include <hip/hip_runtime.h>
#include <hip/hip_bf16.h>

typedef float  f32x4  __attribute__((ext_vector_type(4)));
typedef __bf16 bf16x8 __attribute__((ext_vector_type(8)));
typedef __bf16 bf16x4 __attribute__((ext_vector_type(4)));

#define D_  512
#define H_  8
#define HD_ 64
#define B_  256
#define N_  144
#define M_  (B_*N_)   // 36864

using gptr_t = const __attribute__((address_space(1))) char*;
using lptr_t = __attribute__((address_space(3))) char*;
#define GLDS16(gp, lp) __builtin_amdgcn_global_load_lds((gptr_t)(gp), (lptr_t)(lp), 16, 0, 0)

// ---------------- weight prep: f32 -> bf16 ----------------
__global__ void prep_weights_kernel(const float* __restrict__ kvw,
                                    const float* __restrict__ qw,
                                    const float* __restrict__ pw,
                                    __bf16* __restrict__ kvb,
                                    __bf16* __restrict__ qb,
                                    __bf16* __restrict__ pb) {
    int idx = blockIdx.x * 256 + threadIdx.x;
    const float* s; __bf16* d; int off;
    if (idx < 131072)      { s = kvw; d = kvb; off = idx; }
    else if (idx < 196608) { s = qw;  d = qb;  off = idx - 131072; }
    else                   { s = pw;  d = pb;  off = idx - 196608; }
    f32x4 v = *(const f32x4*)(s + (size_t)off * 4);
    bf16x4 o;
    o[0] = (__bf16)v.x; o[1] = (__bf16)v.y; o[2] = (__bf16)v.z; o[3] = (__bf16)v.w;
    *(bf16x4*)(d + (size_t)off * 4) = o;
}

// ------------- activation prep: xb = bf16(x), ab = bf16(x + tf*topo) -------------
__global__ void prep_act_kernel(const float* __restrict__ x,
                                const float* __restrict__ topo,
                                const int* __restrict__ is_end,
                                __bf16* __restrict__ xb,
                                __bf16* __restrict__ ab) {
    const float tf = (is_end[0] != 0) ? 1.f : 0.f;
    const size_t total = (size_t)M_ * D_ / 8;
    for (size_t i = (size_t)blockIdx.x * 256 + threadIdx.x; i < total;
         i += (size_t)gridDim.x * 256) {
        f32x4 a0 = *(const f32x4*)(x + i * 8);
        f32x4 a1 = *(const f32x4*)(x + i * 8 + 4);
        f32x4 t0 = *(const f32x4*)(topo + i * 8);
        f32x4 t1 = *(const f32x4*)(topo + i * 8 + 4);
        bf16x8 xo, ao;
#pragma unroll
        for (int j = 0; j < 4; ++j) {
            xo[j]     = (__bf16)a0[j];
            xo[j + 4] = (__bf16)a1[j];
            ao[j]     = (__bf16)(a0[j] + tf * t0[j]);
            ao[j + 4] = (__bf16)(a1[j] + tf * t1[j]);
        }
        *(bf16x8*)(xb + i * 8) = xo;
        *(bf16x8*)(ab + i * 8) = ao;
    }
}

// ======== fused QKV-projection + attention: one block per (batch, head) ========
// Phase A: [K|V](144x128) = ab_bb @ [Wk_h;Wv_h]^T -> Ks[144][72], Vt[64][168] (LDS)
// Phase B: Q(144x64)      = xb_bb @ Wq_h^T        -> Qs[144][72] (LDS)
// Phase C: R7 attention body reading Qs/Ks/Vt; Ps overlays the staging region.
// KVQ never touches HBM (saves 113 MB write + 113 MB read vs mm0+attn pipeline).
// Staging: R8-verified swizzled-source glds (byte ^= (row&7)<<4), linear LDS dest.
__global__ __launch_bounds__(256, 2) void fused_kernel(
        const __bf16* __restrict__ ab, const __bf16* __restrict__ xb,
        const __bf16* __restrict__ kvb, const __bf16* __restrict__ qb,
        __bf16* __restrict__ aout) {
    __shared__ __align__(16) char smem[97792];
    char* SA = smem;                 // staged A: 144 rows x 128B (swizzled cols)
    char* SB = smem + 18432;         // staged B: <=128 rows x 128B
    __bf16 (*Qs)[72]  = (__bf16 (*)[72])(smem + 34816);
    __bf16 (*Ks)[72]  = (__bf16 (*)[72])(smem + 55552);
    __bf16 (*Vt)[168] = (__bf16 (*)[168])(smem + 76288);
    __bf16 (*Ps)[16][168] = (__bf16 (*)[16][168])smem;  // after GEMMs, SA/SB dead

    const int tid  = threadIdx.x;
    const int lane = tid & 63, wid = tid >> 6;
    const int lrow = lane & 15, lhi = lane >> 4;

    const int bid = blockIdx.x;
    const int wg  = (bid & 7) * 256 + (bid >> 3);  // XCD-chunked: same bb -> same XCD
    const int bb  = wg >> 3, hh = wg & 7;

    const char* Aab = (const char*)(ab + (size_t)bb * N_ * D_);
    const char* Axb = (const char*)(xb + (size_t)bb * N_ * D_);
    const char* Wk  = (const char*)(kvb + (size_t)hh * HD_ * D_);
    const char* Wv  = (const char*)(kvb + (size_t)(512 + hh * HD_) * D_);
    const char* Wq  = (const char*)(qb  + (size_t)hh * HD_ * D_);

    const int crow = lane >> 3;                       // row within 8-row chunk
    const int scb  = ((lane & 7) * 16) ^ (crow << 4); // swizzled source byte col
    const unsigned rsw = (unsigned)((lrow & 7) << 4); // read-side swizzle
    const unsigned cb0 = (0u + lhi * 16) ^ rsw;       // kk=0 byte col
    const unsigned cb1 = (64u + lhi * 16) ^ rsw;      // kk=1 byte col

    // ---------- Phase A ----------
    f32x4 acc[9][2];
#pragma unroll
    for (int i = 0; i < 9; ++i) { acc[i][0] = (f32x4){0,0,0,0}; acc[i][1] = (f32x4){0,0,0,0}; }

    for (int kt = 0; kt < 8; ++kt) {
        const int kb = kt * 128;
#pragma unroll
        for (int it = 0; it < 4; ++it) {              // As: chunks 0..15
            int cc = wid * 4 + it;
            GLDS16(Aab + (size_t)(cc * 8 + crow) * 1024 + kb + scb, SA + cc * 1024);
        }
        if (wid < 2)                                  // As: chunks 16,17
            GLDS16(Aab + (size_t)((16 + wid) * 8 + crow) * 1024 + kb + scb,
                   SA + (16 + wid) * 1024);
#pragma unroll
        for (int it = 0; it < 4; ++it) {              // Bs: 16 chunks (K rows then V rows)
            int cc = wid * 4 + it;
            int r  = cc * 8 + crow;
            const char* src = (cc < 8) ? (Wk + (size_t)r * 1024)
                                       : (Wv + (size_t)(r - 64) * 1024);
            GLDS16(src + kb + scb, SB + cc * 1024);
        }
        __syncthreads();
#pragma unroll
        for (int mi = 0; mi < 9; ++mi) {
            const unsigned ra = (unsigned)((mi * 16 + lrow) * 128);
            bf16x8 a0 = *(const bf16x8*)(SA + ra + cb0);
            bf16x8 a1 = *(const bf16x8*)(SA + ra + cb1);
#pragma unroll
            for (int ni = 0; ni < 2; ++ni) {
                const unsigned rb = (unsigned)((wid * 32 + ni * 16 + lrow) * 128);
                acc[mi][ni] = __builtin_amdgcn_mfma_f32_16x16x32_bf16(
                    a0, *(const bf16x8*)(SB + rb + cb0), acc[mi][ni], 0, 0, 0);
                acc[mi][ni] = __builtin_amdgcn_mfma_f32_16x16x32_bf16(
                    a1, *(const bf16x8*)(SB + rb + cb1), acc[mi][ni], 0, 0, 0);
            }
        }
        __syncthreads();
    }
    // epilogue A: waves 0,1 -> Ks ; waves 2,3 -> Vt (transposed, bf16x4-packed)
    if (wid < 2) {
#pragma unroll
        for (int mi = 0; mi < 9; ++mi)
#pragma unroll
            for (int ni = 0; ni < 2; ++ni)
#pragma unroll
                for (int reg = 0; reg < 4; ++reg)
                    Ks[mi * 16 + lhi * 4 + reg][wid * 32 + ni * 16 + lrow] =
                        (__bf16)acc[mi][ni][reg];
    } else {
#pragma unroll
        for (int mi = 0; mi < 9; ++mi)
#pragma unroll
            for (int ni = 0; ni < 2; ++ni) {
                int d = (wid - 2) * 32 + ni * 16 + lrow;
                bf16x4 p;
#pragma unroll
                for (int reg = 0; reg < 4; ++reg) p[reg] = (__bf16)acc[mi][ni][reg];
                *(bf16x4*)&Vt[d][mi * 16 + lhi * 4] = p;
            }
    }
    // zero Vt pad cols 144..167
    for (int c = tid; c < 192; c += 256) {
        bf16x8 z8;
#pragma unroll
        for (int i = 0; i < 8; ++i) z8[i] = (__bf16)0.f;
        *(bf16x8*)&Vt[c / 3][144 + (c % 3) * 8] = z8;
    }

    // ---------- Phase B ----------
    f32x4 acq[9];
#pragma unroll
    for (int i = 0; i < 9; ++i) acq[i] = (f32x4){0,0,0,0};

    for (int kt = 0; kt < 8; ++kt) {
        const int kb = kt * 128;
#pragma unroll
        for (int it = 0; it < 4; ++it) {
            int cc = wid * 4 + it;
            GLDS16(Axb + (size_t)(cc * 8 + crow) * 1024 + kb + scb, SA + cc * 1024);
        }
        if (wid < 2)
            GLDS16(Axb + (size_t)((16 + wid) * 8 + crow) * 1024 + kb + scb,
                   SA + (16 + wid) * 1024);
#pragma unroll
        for (int it = 0; it < 2; ++it) {              // Bs2: 8 chunks (Wq rows)
            int cc = wid * 2 + it;
            GLDS16(Wq + (size_t)(cc * 8 + crow) * 1024 + kb + scb, SB + cc * 1024);
        }
        __syncthreads();
        {
            const unsigned rb = (unsigned)((wid * 16 + lrow) * 128);
            bf16x8 b0 = *(const bf16x8*)(SB + rb + cb0);
            bf16x8 b1 = *(const bf16x8*)(SB + rb + cb1);
#pragma unroll
            for (int mi = 0; mi < 9; ++mi) {
                const unsigned ra = (unsigned)((mi * 16 + lrow) * 128);
                acq[mi] = __builtin_amdgcn_mfma_f32_16x16x32_bf16(
                    *(const bf16x8*)(SA + ra + cb0), b0, acq[mi], 0, 0, 0);
                acq[mi] = __builtin_amdgcn_mfma_f32_16x16x32_bf16(
                    *(const bf16x8*)(SA + ra + cb1), b1, acq[mi], 0, 0, 0);
            }
        }
        __syncthreads();
    }
    // epilogue B: Qs
#pragma unroll
    for (int mi = 0; mi < 9; ++mi)
#pragma unroll
        for (int reg = 0; reg < 4; ++reg)
            Qs[mi * 16 + lhi * 4 + reg][wid * 16 + lrow] = (__bf16)acq[mi][reg];

    __syncthreads();   // KVQ visible to all waves; SA/SB now free for Ps

    // ---------- Phase C: attention (R7 body, LDS sources) ----------
    {
        bf16x8 z8;
#pragma unroll
        for (int i = 0; i < 8; ++i) z8[i] = (__bf16)0.f;
        if (lhi < 2)
            *(bf16x8*)&Ps[wid][lrow][144 + lhi * 8] = z8;
    }
    const float sc = 0.125f * 1.44269504089f;     // scale * log2(e)

    for (int t = wid; t < 9; t += 4) {
        bf16x8 aq[2];
#pragma unroll
        for (int kk = 0; kk < 2; ++kk)
            aq[kk] = *(const bf16x8*)&Qs[t * 16 + lrow][kk * 32 + lhi * 8];

        f32x4 s[9];
#pragma unroll
        for (int j = 0; j < 9; ++j) s[j] = (f32x4){0,0,0,0};
#pragma unroll
        for (int j = 0; j < 9; ++j)
#pragma unroll
            for (int kk = 0; kk < 2; ++kk)
                s[j] = __builtin_amdgcn_mfma_f32_16x16x32_bf16(
                    aq[kk], *(const bf16x8*)&Ks[j * 16 + lrow][kk * 32 + lhi * 8],
                    s[j], 0, 0, 0);

        float inv[4];
#pragma unroll
        for (int reg = 0; reg < 4; ++reg) {
            float mx = s[0][reg];
#pragma unroll
            for (int j = 1; j < 9; ++j) mx = fmaxf(mx, s[j][reg]);
#pragma unroll
            for (int off = 1; off < 16; off <<= 1) mx = fmaxf(mx, __shfl_xor(mx, off, 16));
            float sum = 0.f;
#pragma unroll
            for (int j = 0; j < 9; ++j) {
                float p = exp2f((s[j][reg] - mx) * sc);
                s[j][reg] = p;
                sum += p;
            }
#pragma unroll
            for (int off = 1; off < 16; off <<= 1) sum += __shfl_xor(sum, off, 16);
            inv[reg] = 1.f / sum;
        }
#pragma unroll
        for (int j = 0; j < 9; ++j)
#pragma unroll
            for (int reg = 0; reg < 4; ++reg)
                Ps[wid][lhi * 4 + reg][j * 16 + lrow] = (__bf16)(s[j][reg] * inv[reg]);

#pragma unroll
        for (int dc = 0; dc < 4; ++dc) {
            f32x4 o4 = (f32x4){0,0,0,0};
#pragma unroll
            for (int kc = 0; kc < 5; ++kc)
                o4 = __builtin_amdgcn_mfma_f32_16x16x32_bf16(
                    *(const bf16x8*)&Ps[wid][lrow][kc * 32 + lhi * 8],
                    *(const bf16x8*)&Vt[dc * 16 + lrow][kc * 32 + lhi * 8],
                    o4, 0, 0, 0);
#pragma unroll
            for (int reg = 0; reg < 4; ++reg) {
                int nn = t * 16 + lhi * 4 + reg;
                int dd = dc * 16 + lrow;
                aout[((size_t)bb * N_ + nn) * D_ + hh * HD_ + dd] = (__bf16)o4[reg];
            }
        }
    }
}

// ---------------- mm1: out-proj, 2-phase 128x128 (R7, unchanged) ----------------
__global__ __launch_bounds__(256, 3) void mm1_kernel(
        const __bf16* __restrict__ abuf, const __bf16* __restrict__ pwb,
        const float* __restrict__ bias, float* __restrict__ pout) {
    __shared__ __align__(16) char smem[32768];
    __bf16* As = (__bf16*)smem;
    __bf16* Bs = (__bf16*)(smem + 16384);

    const int tid  = threadIdx.x;
    const int lane = tid & 63, wid = tid >> 6;
    const int lrow = lane & 15, lhi = lane >> 4;
    const int wr   = wid >> 1,  wc  = wid & 1;

    const int bid = blockIdx.x;
    const int wg  = (bid & 7) * 144 + (bid >> 3);
    const int mb  = wg / 4;
    const int nb  = wg - mb * 4;
    const int m0  = mb * 128;

    const __bf16* Ap = abuf;
    const __bf16* Bp = pwb + (size_t)nb * 128 * D_;

    f32x4 acc[4][4];
#pragma unroll
    for (int i = 0; i < 4; ++i)
#pragma unroll
        for (int j = 0; j < 4; ++j) acc[i][j] = (f32x4){0.f, 0.f, 0.f, 0.f};

    const int srow = lane >> 3;
    const int scol = (lane & 7) * 16;

    for (int kt = 0; kt < 8; ++kt) {
        const int k0 = kt * 64;
        const char* Agb = (const char*)(Ap + (size_t)m0 * D_ + k0);
        const char* Bgb = (const char*)(Bp + k0);
#pragma unroll
        for (int j = 0; j < 4; ++j) {
            const int chunk = wid * 4 + j;
            const int row   = chunk * 8 + srow;
            GLDS16(Agb + (size_t)row * (D_ * 2) + scol, (char*)As + chunk * 1024);
            GLDS16(Bgb + (size_t)row * (D_ * 2) + scol, (char*)Bs + chunk * 1024);
        }
        __syncthreads();
#pragma unroll
        for (int kk = 0; kk < 2; ++kk) {
            bf16x8 af[4], bfr[4];
#pragma unroll
            for (int mi = 0; mi < 4; ++mi)
                af[mi] = *(const bf16x8*)((const char*)As +
                          (wr * 64 + mi * 16 + lrow) * 128 + kk * 64 + lhi * 16);
#pragma unroll
            for (int ni = 0; ni < 4; ++ni)
                bfr[ni] = *(const bf16x8*)((const char*)Bs +
                          (wc * 64 + ni * 16 + lrow) * 128 + kk * 64 + lhi * 16);
#pragma unroll
            for (int mi = 0; mi < 4; ++mi)
#pragma unroll
                for (int ni = 0; ni < 4; ++ni)
                    acc[mi][ni] = __builtin_amdgcn_mfma_f32_16x16x32_bf16(
                        af[mi], bfr[ni], acc[mi][ni], 0, 0, 0);
        }
        __syncthreads();
    }

    float bv4[4];
#pragma unroll
    for (int ni = 0; ni < 4; ++ni) bv4[ni] = bias[nb * 128 + wc * 64 + ni * 16 + lrow];
#pragma unroll
    for (int mi = 0; mi < 4; ++mi)
#pragma unroll
        for (int reg = 0; reg < 4; ++reg) {
            int m = m0 + wr * 64 + mi * 16 + lhi * 4 + reg;
#pragma unroll
            for (int ni = 0; ni < 4; ++ni)
                pout[(size_t)m * D_ + nb * 128 + wc * 64 + ni * 16 + lrow] =
                    acc[mi][ni][reg] + bv4[ni];
        }
}

extern "C" void kernel_launch(void* const* d_in, const int* in_sizes, int n_in,
                              void* d_out, int out_size, void* d_ws, size_t ws_size,
                              hipStream_t stream) {
    const float* x      = (const float*)d_in[0];
    const float* topo   = (const float*)d_in[1];
    const float* kvw    = (const float*)d_in[2];
    const float* qw     = (const float*)d_in[3];
    const float* pw     = (const float*)d_in[4];
    const float* pb     = (const float*)d_in[5];
    const int*   is_end = (const int*)d_in[6];
    float* out = (float*)d_out;

    char* ws = (char*)d_ws;
    __bf16* kvb = (__bf16*)(ws);                       // 1 MiB
    __bf16* qb  = (__bf16*)(ws + (1u << 20));          // 512 KiB
    __bf16* pwb = (__bf16*)(ws + (1u << 20) + 524288); // 512 KiB
    size_t off = (1u << 20) + 2 * 524288;
    const size_t BUF = (size_t)M_ * D_ * 2;            // 37748736 B each
    __bf16* xb    = (__bf16*)(ws + off); off += BUF;   // bf16(x)
    __bf16* ab    = (__bf16*)(ws + off); off += BUF;   // bf16(x + tf*topo)
    __bf16* abuf  = (__bf16*)(ws + off); off += BUF;   // attention output

    prep_weights_kernel<<<1024, 256, 0, stream>>>(kvw, qw, pw, kvb, qb, pwb);
    prep_act_kernel<<<2048, 256, 0, stream>>>(x, topo, is_end, xb, ab);
    fused_kernel<<<2048, 256, 0, stream>>>(ab, xb, kvb, qb, abuf);
    mm1_kernel<<<1152, 256, 0, stream>>>(abuf, pwb, pb, out);
}